// Round 16
// baseline (2072.336 us; speedup 1.0000x reference)
//
#include <hip/hip_runtime.h>
#include <hip/hip_bf16.h>

#define T_ 1024
#define B_ 64
#define H_ 128
#define G_ 512   // 4*H
#define E_ 128
#define V_ 32
#define N_ 8

// ---- cross-lane helpers (compile-time controls) ---------------------------
template<int CTRL>
__device__ __forceinline__ float dppf(float x) {
    return __int_as_float(__builtin_amdgcn_update_dpp(0, __float_as_int(x), CTRL, 0xF, 0xF, true));
}
template<int CTRL>
__device__ __forceinline__ int dppi(int x) {
    return __builtin_amdgcn_update_dpp(0, x, CTRL, 0xF, 0xF, true);
}
template<int OFF>
__device__ __forceinline__ float swzf(float x) {
    return __int_as_float(__builtin_amdgcn_ds_swizzle(__float_as_int(x), OFF));
}
// DPP ctrl constants: quad_perm[a,b,c,d] = a|b<<2|c<<4|d<<6
#define QP_XOR1 0xB1   // [1,0,3,2]  == exact lane^1 exchange
#define QP_XOR2 0x4E   // [2,3,0,1]  == exact lane^2 exchange
#define QP_BC0  0x00
#define QP_BC1  0x55
#define QP_BC2  0xAA
#define QP_BC3  0xFF
#define ROW_ROR8 0x128 // row_ror:8 == exact lane^8 exchange within 16-row
// ds_swizzle BitMode: (xor<<10)|(or<<5)|and
#define SWZ_XOR4  0x101F
#define SWZ_XOR16 0x401F

// ---------------------------------------------------------------------------
// K0: proj[dir][v][g] = b_dir[g] + sum_e W_ih_dir[g][e] * emb[v][e]
// (verbatim — passing)
// ---------------------------------------------------------------------------
__global__ __launch_bounds__(512) void proj_kernel(
    const float* __restrict__ emb,
    const float* __restrict__ Wih_f, const float* __restrict__ b_f,
    const float* __restrict__ Wih_b, const float* __restrict__ b_b,
    float* __restrict__ proj)
{
    int wg  = blockIdx.x;
    int dir = wg >> 5;
    int v   = wg & 31;
    const float* W    = dir ? Wih_b : Wih_f;
    const float* bias = dir ? b_b   : b_f;
    int tid = threadIdx.x;

    __shared__ float4 e_l[E_ / 4];
    if (tid < E_ / 4) e_l[tid] = ((const float4*)(emb + (size_t)v * E_))[tid];
    __syncthreads();

    float acc = bias[tid];
    const float4* wr = (const float4*)(W + (size_t)tid * E_);
#pragma unroll
    for (int k = 0; k < 32; ++k) {
        float4 wv = wr[k], ev = e_l[k];
        acc += wv.x * ev.x;
        acc += wv.y * ev.y;
        acc += wv.z * ev.z;
        acc += wv.w * ev.w;
    }
    proj[((size_t)dir * V_ + v) * G_ + tid] = acc;
}

// ---------------------------------------------------------------------------
// K1: LSTM — TWO batch chains per block (same dir => same W, streamed once,
// used twice: halves per-chain L2 traffic; r12's stream was the 983 ns/step
// wall). grid 64 = dir*32 + pair; chains bA=2*pair, bB=2*pair+1.
// Thread (j=tid>>3, q=tid&7): gate pair p=q&1 (rows 2p,2p+1), h-chunk
// c=q>>1 — per-chain math bit-identical to the passing r12/r15 kernel.
// FC: 16 waves — waves 0-7 chain A logit nw, waves 8-15 chain B logit nw.
// ---------------------------------------------------------------------------
__global__ __launch_bounds__(1024)
__attribute__((amdgpu_waves_per_eu(4, 4)))
void lstm_kernel(
    const int*   __restrict__ x,
    const float* __restrict__ Whh_f, const float* __restrict__ Whh_b,
    const float* __restrict__ proj,   // [2][V][G]
    const float* __restrict__ fcW,    // [8][256]
    float* __restrict__ part)         // [2][T][B][8]
{
    int wg  = blockIdx.x;
    int dir = wg >> 5;
    int pr  = wg & 31;
    int bA  = 2 * pr;
    int bB  = 2 * pr + 1;
    int tid = threadIdx.x;
    int j   = tid >> 3;        // 0..127
    int q   = tid & 7;
    int p   = q & 1;           // gate pair -> rows {2p, 2p+1}
    int c   = q >> 1;          // h-chunk 0..3
    int which = c & 1;         // own gate within pair
    int gate_own = 2 * p + which;   // quad positions {0,1,2,3} -> gates {0,2,1,3}

    __shared__ union { int tok[2][T_]; char pad[83 * 1024]; } tu;  // forcer
    __shared__ float4 hbA4[2][H_ / 4];   // chain A double-buffered h
    __shared__ float4 hbB4[2][H_ / 4];   // chain B double-buffered h

    tu.tok[0][tid] = x[(size_t)bA * T_ + tid];
    tu.tok[1][tid] = x[(size_t)bB * T_ + tid];
    if (tid < H_) ((float*)hbA4[0])[tid] = 0.f;
    else if (tid < 2 * H_) ((float*)hbB4[0])[tid - H_] = 0.f;

    int nw = (tid >> 6) & 7;   // FC logit
    int cs = tid >> 9;         // FC chain select (0: A, 1: B)
    int e  = tid & 63;         // FC element pair
    float fw0 = fcW[nw * 256 + dir * H_ + 2 * e];
    float fw1 = fcW[nw * 256 + dir * H_ + 2 * e + 1];

    const float* Whh = dir ? Whh_b : Whh_f;

    // w0/w1[k] = W_hh[(2p / 2p+1)*128+j][ c*32 + ((k+2c)&7)*4 .. +4 )
    float4 w0[8], w1[8];
    {
        const float4* wr0 = (const float4*)(Whh + (size_t)((2 * p) * H_ + j) * H_ + c * 32);
        const float4* wr1 = (const float4*)(Whh + (size_t)((2 * p + 1) * H_ + j) * H_ + c * 32);
#pragma unroll
        for (int k = 0; k < 8; ++k) {
            w0[k] = wr0[(k + 2 * c) & 7];
            w1[k] = wr1[(k + 2 * c) & 7];
        }
    }
#pragma unroll
    for (int k = 0; k < 8; ++k) {
        asm volatile("" : "+v"(w0[k].x), "+v"(w0[k].y), "+v"(w0[k].z), "+v"(w0[k].w));
        asm volatile("" : "+v"(w1[k].x), "+v"(w1[k].y), "+v"(w1[k].z), "+v"(w1[k].w));
    }
    asm volatile("" : "+v"(fw0), "+v"(fw1));

    const float* projd = proj + (size_t)dir * (V_ * G_);
    int gown = gate_own * H_ + j;
    float ccA = 0.f, ccB = 0.f;
    __syncthreads();

    int t0i = dir ? (T_ - 1) : 0;
    float pvA_c = projd[tu.tok[0][t0i] * G_ + gown];
    float pvB_c = projd[tu.tok[1][t0i] * G_ + gown];

    int cur = 0;
    for (int t = 0; t < T_; ++t) {
        int tt = dir ? (T_ - 1 - t) : t;
        int tn = (t + 1 < T_) ? (t + 1) : t;
        int ttn = dir ? (T_ - 1 - tn) : tn;
        float pvA_n = projd[tu.tok[0][ttn] * G_ + gown];
        float pvB_n = projd[tu.tok[1][ttn] * G_ + gown];

        const float4* hbA = (const float4*)hbA4[cur];
        const float4* hbB = (const float4*)hbB4[cur];
        float a0A = 0.f, a1A = 0.f, a0B = 0.f, a1B = 0.f;
#pragma unroll
        for (int k = 0; k < 8; ++k) {
            int hidx = c * 8 + ((k + 2 * c) & 7);
            float4 hvA = hbA[hidx];
            float4 hvB = hbB[hidx];
            float4 u0 = w0[k], u1 = w1[k];
            a0A += u0.x * hvA.x; a0A += u0.y * hvA.y; a0A += u0.z * hvA.z; a0A += u0.w * hvA.w;
            a1A += u1.x * hvA.x; a1A += u1.y * hvA.y; a1A += u1.z * hvA.z; a1A += u1.w * hvA.w;
            a0B += u0.x * hvB.x; a0B += u0.y * hvB.y; a0B += u0.z * hvB.z; a0B += u0.w * hvB.w;
            a1B += u1.x * hvB.x; a1B += u1.y * hvB.y; a1B += u1.z * hvB.z; a1B += u1.w * hvB.w;
        }
        // per-chain reduce: XOR2 (DPP) then XOR4 (swizzle) — r12 tree
        a0A += dppf<QP_XOR2>(a0A); a1A += dppf<QP_XOR2>(a1A);
        a0B += dppf<QP_XOR2>(a0B); a1B += dppf<QP_XOR2>(a1B);
        a0A += swzf<SWZ_XOR4>(a0A); a1A += swzf<SWZ_XOR4>(a1A);
        a0B += swzf<SWZ_XOR4>(a0B); a1B += swzf<SWZ_XOR4>(a1B);

        float totA = which ? a1A : a0A;  totA += pvA_c;
        float totB = which ? a1B : a0B;  totB += pvB_c;
        float actA = (gate_own == 2) ? tanhf(totA) : 1.f / (1.f + expf(-totA));
        float actB = (gate_own == 2) ? tanhf(totB) : 1.f / (1.f + expf(-totB));

        // quad positions {0,1,2,3} hold gates {i,g,f,o} -> broadcast-gather
        float giA = dppf<QP_BC0>(actA), ggA = dppf<QP_BC1>(actA);
        float gfA = dppf<QP_BC2>(actA), goA = dppf<QP_BC3>(actA);
        float giB = dppf<QP_BC0>(actB), ggB = dppf<QP_BC1>(actB);
        float gfB = dppf<QP_BC2>(actB), goB = dppf<QP_BC3>(actB);

        ccA = gfA * ccA + giA * ggA;
        ccB = gfB * ccB + giB * ggB;
        float hA = goA * tanhf(ccA);
        float hB = goB * tanhf(ccB);
        if (q == 0) {
            ((float*)hbA4[cur ^ 1])[j] = hA;
            ((float*)hbB4[cur ^ 1])[j] = hB;
        }
        __syncthreads();                   // single barrier per step

        // FC: wave w<8 -> chain A logit nw; wave w>=8 -> chain B logit nw
        {
            const float2* hsrc = cs ? (const float2*)hbB4[cur ^ 1]
                                    : (const float2*)hbA4[cur ^ 1];
            float2 h2 = hsrc[e];
            float pa = fw0 * h2.x + fw1 * h2.y;
            pa += dppf<QP_XOR1>(pa);
            pa += dppf<QP_XOR2>(pa);
            pa += swzf<SWZ_XOR4>(pa);
            pa += dppf<ROW_ROR8>(pa);
            pa += swzf<SWZ_XOR16>(pa);
            float psum = pa + __int_as_float(__builtin_amdgcn_readlane(__float_as_int(pa), 32));
            if (e == 0) {
                int bsel = cs ? bB : bA;
                part[(((size_t)dir * T_ + tt) * B_ + bsel) * N_ + nw] = psum;
            }
        }
        pvA_c = pvA_n;
        pvB_c = pvB_n;
        cur ^= 1;
    }
}

// ---------------------------------------------------------------------------
// K2: Viterbi — round-15 replicated-score all-DPP version VERBATIM (passing).
// ---------------------------------------------------------------------------
__global__ __launch_bounds__(64) void viterbi_kernel(
    const float* __restrict__ part,   // [2][T][B][8]
    const float* __restrict__ fc_b,
    const float* __restrict__ start_t,
    const float* __restrict__ end_t,
    const float* __restrict__ trans,  // [8][8]
    int* __restrict__ out)            // [B][T]
{
    int b = blockIdx.x;
    int l = threadIdx.x;
    int j = (l & 3) | ((l >> 1) & 4);
    bool b0c = (l & 1) != 0;
    bool b1c = (l & 2) != 0;
    bool b3c = (l & 8) != 0;
    int sh3 = 3 * j;

    __shared__ unsigned int hist_l[T_];

    float tr[8];
#pragma unroll
    for (int i = 0; i < 8; ++i) tr[i] = trans[i * 8 + j];   // column j
    float endt_r[8];
#pragma unroll
    for (int i = 0; i < 8; ++i) endt_r[i] = end_t[i];
    float fcb = fc_b[j];
    const float* pf = part;
    const float* pb = part + (size_t)T_ * B_ * N_;

    float s[8];

#define SHARE(xx) { \
    float y_ = dppf<QP_XOR1>(xx); \
    float A0 = b0c ? y_ : (xx); float A1 = b0c ? (xx) : y_; \
    float A0x = dppf<QP_XOR2>(A0); float A1x = dppf<QP_XOR2>(A1); \
    float B00 = b1c ? A0x : A0; float B10 = b1c ? A0 : A0x; \
    float B01 = b1c ? A1x : A1; float B11 = b1c ? A1 : A1x; \
    float C00 = dppf<ROW_ROR8>(B00); float C01 = dppf<ROW_ROR8>(B01); \
    float C10 = dppf<ROW_ROR8>(B10); float C11 = dppf<ROW_ROR8>(B11); \
    s[0] = b3c ? C00 : B00;  s[1] = b3c ? C01 : B01; \
    s[2] = b3c ? C10 : B10;  s[3] = b3c ? C11 : B11; \
    s[4] = b3c ? B00 : C00;  s[5] = b3c ? B01 : C01; \
    s[6] = b3c ? B10 : C10;  s[7] = b3c ? B11 : C11; }

#define VSTEP(emv, tcur) { \
    float v0 = (s[0] + tr[0]) + (emv); \
    float v1 = (s[1] + tr[1]) + (emv); \
    float v2 = (s[2] + tr[2]) + (emv); \
    float v3 = (s[3] + tr[3]) + (emv); \
    float v4 = (s[4] + tr[4]) + (emv); \
    float v5 = (s[5] + tr[5]) + (emv); \
    float v6 = (s[6] + tr[6]) + (emv); \
    float v7 = (s[7] + tr[7]) + (emv); \
    float va = (v1 > v0) ? v1 : v0;  int ia = (v1 > v0) ? 1 : 0; \
    float vb = (v3 > v2) ? v3 : v2;  int ib = (v3 > v2) ? 3 : 2; \
    float vc = (v5 > v4) ? v5 : v4;  int ic = (v5 > v4) ? 5 : 4; \
    float vd = (v7 > v6) ? v7 : v6;  int id_ = (v7 > v6) ? 7 : 6; \
    float ve = (vb > va) ? vb : va;  int ie = (vb > va) ? ib : ia; \
    float vf = (vd > vc) ? vd : vc;  int if_ = (vd > vc) ? id_ : ic; \
    float vg = (vf > ve) ? vf : ve;  int ig = (vf > ve) ? if_ : ie; \
    SHARE(vg) \
    unsigned pk = (unsigned)ig << sh3; \
    pk |= (unsigned)dppi<QP_XOR1>((int)pk); \
    pk |= (unsigned)dppi<QP_XOR2>((int)pk); \
    pk |= (unsigned)dppi<ROW_ROR8>((int)pk); \
    if (l == 0) hist_l[tcur] = pk; }

#define LOADSUB(dst, ss) { \
    int t0_ = (ss) * 8; \
    _Pragma("unroll") \
    for (int p = 0; p < 8; ++p) { \
        size_t base = ((size_t)(t0_ + p) * B_ + b) * N_ + j; \
        dst[p] = (pf[base] + pb[base]) + fcb; } }

#define PROC8(arr, t0_) { \
    VSTEP(arr[0], (t0_) + 0) VSTEP(arr[1], (t0_) + 1) \
    VSTEP(arr[2], (t0_) + 2) VSTEP(arr[3], (t0_) + 3) \
    VSTEP(arr[4], (t0_) + 4) VSTEP(arr[5], (t0_) + 5) \
    VSTEP(arr[6], (t0_) + 6) VSTEP(arr[7], (t0_) + 7) }

    float emA[8], emB[8];
    LOADSUB(emA, 0)
    LOADSUB(emB, 1)

    {
        float x0 = start_t[j] + emA[0];
        SHARE(x0)
    }
    VSTEP(emA[1], 1) VSTEP(emA[2], 2) VSTEP(emA[3], 3) VSTEP(emA[4], 4)
    VSTEP(emA[5], 5) VSTEP(emA[6], 6) VSTEP(emA[7], 7)

    for (int ss = 1; ss < 127; ss += 2) {
        LOADSUB(emA, ss + 1)
        PROC8(emB, ss * 8)
        LOADSUB(emB, ss + 2)
        PROC8(emA, (ss + 1) * 8)
    }
    PROC8(emB, 127 * 8)

    int tag;
    {
        float v0 = s[0] + endt_r[0];
        float v1 = s[1] + endt_r[1];
        float v2 = s[2] + endt_r[2];
        float v3 = s[3] + endt_r[3];
        float v4 = s[4] + endt_r[4];
        float v5 = s[5] + endt_r[5];
        float v6 = s[6] + endt_r[6];
        float v7 = s[7] + endt_r[7];
        float va = (v1 > v0) ? v1 : v0;  int ia = (v1 > v0) ? 1 : 0;
        float vb = (v3 > v2) ? v3 : v2;  int ib = (v3 > v2) ? 3 : 2;
        float vc = (v5 > v4) ? v5 : v4;  int ic = (v5 > v4) ? 5 : 4;
        float vd = (v7 > v6) ? v7 : v6;  int id_ = (v7 > v6) ? 7 : 6;
        float ve = (vb > va) ? vb : va;  int ie = (vb > va) ? ib : ia;
        float vf = (vd > vc) ? vd : vc;  int if_ = (vd > vc) ? id_ : ic;
        tag = (vf > ve) ? if_ : ie;
    }
    if (l == 0) out[(size_t)b * T_ + (T_ - 1)] = tag;
    __syncthreads();

    for (int t0b = T_ - 16; t0b >= 0; t0b -= 16) {
        unsigned int pk[16];
#pragma unroll
        for (int qq = 0; qq < 16; ++qq) pk[qq] = hist_l[t0b + qq];
#pragma unroll
        for (int qq = 15; qq >= 0; --qq) {
            int t = t0b + qq;
            if (t >= 1) {
                tag = (pk[qq] >> (3 * tag)) & 7;
                if (l == 0) out[(size_t)b * T_ + t - 1] = tag;
            }
        }
    }
#undef SHARE
#undef VSTEP
#undef LOADSUB
#undef PROC8
}

extern "C" void kernel_launch(void* const* d_in, const int* in_sizes, int n_in,
                              void* d_out, int out_size, void* d_ws, size_t ws_size,
                              hipStream_t stream) {
    (void)in_sizes; (void)n_in; (void)out_size; (void)ws_size;
    const int*   x      = (const int*)  d_in[0];
    const float* emb    = (const float*)d_in[1];
    const float* Wih_f  = (const float*)d_in[2];
    const float* Whh_f  = (const float*)d_in[3];
    const float* b_f    = (const float*)d_in[4];
    const float* Wih_b  = (const float*)d_in[5];
    const float* Whh_b  = (const float*)d_in[6];
    const float* b_b    = (const float*)d_in[7];
    const float* fcW    = (const float*)d_in[8];
    const float* fcb    = (const float*)d_in[9];
    const float* startt = (const float*)d_in[10];
    const float* endt   = (const float*)d_in[11];
    const float* trans  = (const float*)d_in[12];

    float* proj = (float*)d_ws;                    // 2*32*512 floats = 128 KB
    float* part = proj + 2 * V_ * G_;              // 2*1024*64*8 floats = 4 MB
    int*   out  = (int*)d_out;

    proj_kernel<<<64, 512, 0, stream>>>(emb, Wih_f, b_f, Wih_b, b_b, proj);
    lstm_kernel<<<64, 1024, 0, stream>>>(x, Whh_f, Whh_b, proj, fcW, part);
    viterbi_kernel<<<64, 64, 0, stream>>>(part, fcb, startt, endt, trans, out);
}

// Round 17
// 1309.388 us; speedup vs baseline: 1.5827x; 1.5827x over previous
//
#include <hip/hip_runtime.h>
#include <hip/hip_bf16.h>

#define T_ 1024
#define B_ 64
#define H_ 128
#define G_ 512   // 4*H
#define E_ 128
#define V_ 32
#define N_ 8

// ---- cross-lane helpers (compile-time controls) ---------------------------
template<int CTRL>
__device__ __forceinline__ float dppf(float x) {
    return __int_as_float(__builtin_amdgcn_update_dpp(0, __float_as_int(x), CTRL, 0xF, 0xF, true));
}
template<int CTRL>
__device__ __forceinline__ int dppi(int x) {
    return __builtin_amdgcn_update_dpp(0, x, CTRL, 0xF, 0xF, true);
}
template<int OFF>
__device__ __forceinline__ float swzf(float x) {
    return __int_as_float(__builtin_amdgcn_ds_swizzle(__float_as_int(x), OFF));
}
// DPP ctrl constants: quad_perm[a,b,c,d] = a|b<<2|c<<4|d<<6
#define QP_XOR1 0xB1   // [1,0,3,2]  == exact lane^1 exchange
#define QP_XOR2 0x4E   // [2,3,0,1]  == exact lane^2 exchange
#define QP_BC0  0x00
#define QP_BC1  0x55
#define QP_BC2  0xAA
#define QP_BC3  0xFF
#define ROW_ROR8 0x128 // row_ror:8 == exact lane^8 exchange within 16-row
// ds_swizzle BitMode: (xor<<10)|(or<<5)|and
#define SWZ_XOR4  0x101F
#define SWZ_XOR16 0x401F

// ---------------------------------------------------------------------------
// K0: proj[dir][v][g] = b_dir[g] + sum_e W_ih_dir[g][e] * emb[v][e]
// (verbatim — passing)
// ---------------------------------------------------------------------------
__global__ __launch_bounds__(512) void proj_kernel(
    const float* __restrict__ emb,
    const float* __restrict__ Wih_f, const float* __restrict__ b_f,
    const float* __restrict__ Wih_b, const float* __restrict__ b_b,
    float* __restrict__ proj)
{
    int wg  = blockIdx.x;
    int dir = wg >> 5;
    int v   = wg & 31;
    const float* W    = dir ? Wih_b : Wih_f;
    const float* bias = dir ? b_b   : b_f;
    int tid = threadIdx.x;

    __shared__ float4 e_l[E_ / 4];
    if (tid < E_ / 4) e_l[tid] = ((const float4*)(emb + (size_t)v * E_))[tid];
    __syncthreads();

    float acc = bias[tid];
    const float4* wr = (const float4*)(W + (size_t)tid * E_);
#pragma unroll
    for (int k = 0; k < 32; ++k) {
        float4 wv = wr[k], ev = e_l[k];
        acc += wv.x * ev.x;
        acc += wv.y * ev.y;
        acc += wv.z * ev.z;
        acc += wv.w * ev.w;
    }
    proj[((size_t)dir * V_ + v) * G_ + tid] = acc;
}

// ---------------------------------------------------------------------------
// K1: LSTM — DS-pipe-optimized layout. grid 128 (dir*64+b), block 1024.
// r16 falsified the L2-BW theory (halving blocks doubled time => per-CU
// local wall). r12 accounting: DS pipe ~1870 cyc/step (8 ds_read_b128 of h
// per thread, 16x wave redundancy) was the binding pipe. This round: thread
// (j=tid>>3, q=tid&7) owns ALL 4 gate rows of unit j x 16-float K-segment q
// -> h reads halve to 4x ds_read_b128 in r14's proven conflict-free [8][20]
// padded layout. Quad positions {0,1,2,3} = gates {i,f,g,o}: r12's BC0..3
// act-gather unchanged. Reduce = 8-lane butterfly XOR1+XOR2 (DPP) +
// XOR4 (swizzle). proj folded pre-reduce via r14's proven 0/1 masks.
// ---------------------------------------------------------------------------
__global__ __launch_bounds__(1024)
__attribute__((amdgpu_waves_per_eu(4, 4)))
void lstm_kernel(
    const int*   __restrict__ x,
    const float* __restrict__ Whh_f, const float* __restrict__ Whh_b,
    const float* __restrict__ proj,   // [2][V][G]
    const float* __restrict__ fcW,    // [8][256]
    float* __restrict__ part)         // [2][T][B][8]
{
    int wg  = blockIdx.x;
    int dir = wg >> 6;
    int b   = wg & 63;
    int tid = threadIdx.x;
    int j   = tid >> 3;        // hidden unit 0..127
    int q   = tid & 7;         // K-segment (16 floats)
    int g   = q & 3;           // own gate (0,1,2,3 = i,f,g,o)

    __shared__ union { int tok[T_]; char pad[83 * 1024]; } tu;  // 1-block/CU forcer
    __shared__ __align__(16) float hpad[2][8][20];  // seg s at 80s bytes (conflict-free, r14)

    tu.tok[tid] = x[(size_t)b * T_ + tid];
    if (tid < 320) ((float*)hpad)[tid] = 0.f;   // zero both buffers (+pads)

    int nw = tid >> 6;      // FC logit (waves 0-7)
    int e  = tid & 63;      // FC element pair
    float fw0 = 0.f, fw1 = 0.f;
    if (tid < 512) {
        fw0 = fcW[nw * 256 + dir * H_ + 2 * e];
        fw1 = fcW[nw * 256 + dir * H_ + 2 * e + 1];
    }
    int fc_off = ((2 * e) >> 4) * 20 + ((2 * e) & 15);  // elem idx into hpad buf (r14)

    const float* Whh = dir ? Whh_b : Whh_f;

    // wreg[r][m] = W_hh[r*128+j][ q*16 + m ], m=0..15
    float wreg[4][16];
#pragma unroll
    for (int r = 0; r < 4; ++r) {
        const float4* wr = (const float4*)(Whh + (size_t)(r * H_ + j) * H_ + q * 16);
        float4 v0 = wr[0], v1 = wr[1], v2 = wr[2], v3 = wr[3];
        wreg[r][0]  = v0.x; wreg[r][1]  = v0.y; wreg[r][2]  = v0.z; wreg[r][3]  = v0.w;
        wreg[r][4]  = v1.x; wreg[r][5]  = v1.y; wreg[r][6]  = v1.z; wreg[r][7]  = v1.w;
        wreg[r][8]  = v2.x; wreg[r][9]  = v2.y; wreg[r][10] = v2.z; wreg[r][11] = v2.w;
        wreg[r][12] = v3.x; wreg[r][13] = v3.y; wreg[r][14] = v3.z; wreg[r][15] = v3.w;
    }
#pragma unroll
    for (int r = 0; r < 4; ++r)
#pragma unroll
        for (int m = 0; m < 16; m += 4)
            asm volatile("" : "+v"(wreg[r][m]), "+v"(wreg[r][m + 1]),
                              "+v"(wreg[r][m + 2]), "+v"(wreg[r][m + 3]));
    asm volatile("" : "+v"(fw0), "+v"(fw1));

    const float* projd = proj + (size_t)dir * (V_ * G_);
    int gown = g * H_ + j;           // proj element (gate g, unit j); q and q+4 dup
    // exact one-per-octet proj fold (r14-proven): lane q==r adds pv to a_r
    float m0 = (q == 0) ? 1.f : 0.f;
    float m1 = (q == 1) ? 1.f : 0.f;
    float m2 = (q == 2) ? 1.f : 0.f;
    float m3 = (q == 3) ? 1.f : 0.f;
    float cc = 0.f;
    __syncthreads();

    float pv_c = projd[tu.tok[dir ? (T_ - 1) : 0] * G_ + gown];

    // 16 FMA for gate row r against this lane's h segment (natural order)
#define MVR(r, acc) { \
    acc += wreg[r][0]  * hv0.x; acc += wreg[r][1]  * hv0.y; \
    acc += wreg[r][2]  * hv0.z; acc += wreg[r][3]  * hv0.w; \
    acc += wreg[r][4]  * hv1.x; acc += wreg[r][5]  * hv1.y; \
    acc += wreg[r][6]  * hv1.z; acc += wreg[r][7]  * hv1.w; \
    acc += wreg[r][8]  * hv2.x; acc += wreg[r][9]  * hv2.y; \
    acc += wreg[r][10] * hv2.z; acc += wreg[r][11] * hv2.w; \
    acc += wreg[r][12] * hv3.x; acc += wreg[r][13] * hv3.y; \
    acc += wreg[r][14] * hv3.z; acc += wreg[r][15] * hv3.w; }

    int cur = 0;
    for (int t = 0; t < T_; ++t) {
        int tt = dir ? (T_ - 1 - t) : t;
        int tn = (t + 1 < T_) ? (t + 1) : t;
        float pv_n = projd[tu.tok[dir ? (T_ - 1 - tn) : tn] * G_ + gown];

        const float* hc = &hpad[cur][q][0];
        float4 hv0 = *(const float4*)(hc);
        float4 hv1 = *(const float4*)(hc + 4);
        float4 hv2 = *(const float4*)(hc + 8);
        float4 hv3 = *(const float4*)(hc + 12);

        float a0 = 0.f, a1 = 0.f, a2 = 0.f, a3 = 0.f;
        MVR(0, a0) MVR(1, a1) MVR(2, a2) MVR(3, a3)

        // fold proj (exactly once per gate across the octet)
        a0 += pv_c * m0; a1 += pv_c * m1; a2 += pv_c * m2; a3 += pv_c * m3;

        // 8-lane butterfly per gate: XOR1, XOR2 (DPP) + XOR4 (swizzle)
        a0 += dppf<QP_XOR1>(a0); a0 += dppf<QP_XOR2>(a0); a0 += swzf<SWZ_XOR4>(a0);
        a1 += dppf<QP_XOR1>(a1); a1 += dppf<QP_XOR2>(a1); a1 += swzf<SWZ_XOR4>(a1);
        a2 += dppf<QP_XOR1>(a2); a2 += dppf<QP_XOR2>(a2); a2 += swzf<SWZ_XOR4>(a2);
        a3 += dppf<QP_XOR1>(a3); a3 += dppf<QP_XOR2>(a3); a3 += swzf<SWZ_XOR4>(a3);

        // lane activates gate g = q&3; quad positions {0,1,2,3} = {i,f,g,o}
        float tot = (g == 0) ? a0 : (g == 1) ? a1 : (g == 2) ? a2 : a3;
        float act = (g == 2) ? tanhf(tot) : 1.f / (1.f + expf(-tot));

        float gi = dppf<QP_BC0>(act);
        float gf = dppf<QP_BC1>(act);
        float gg = dppf<QP_BC2>(act);
        float go = dppf<QP_BC3>(act);

        cc = gf * cc + gi * gg;
        float h = go * tanhf(cc);
        if (q == 0) hpad[cur ^ 1][j >> 4][j & 15] = h;
        __syncthreads();                   // single barrier per step

        // FC on waves 0-7: wave nw computes logit nw (2 FMA + butterfly)
        if (tid < 512) {
            float2 h2 = *(const float2*)&(((const float*)hpad[cur ^ 1])[fc_off]);
            float pa = fw0 * h2.x + fw1 * h2.y;
            pa += dppf<QP_XOR1>(pa);
            pa += dppf<QP_XOR2>(pa);
            pa += swzf<SWZ_XOR4>(pa);
            pa += dppf<ROW_ROR8>(pa);
            pa += swzf<SWZ_XOR16>(pa);
            float psum = pa + __int_as_float(__builtin_amdgcn_readlane(__float_as_int(pa), 32));
            if (e == 0) part[(((size_t)dir * T_ + tt) * B_ + b) * N_ + nw] = psum;
        }
        pv_c = pv_n;
        cur ^= 1;
    }
#undef MVR
}

// ---------------------------------------------------------------------------
// K2: Viterbi — round-15 replicated-score all-DPP version VERBATIM (passing).
// ---------------------------------------------------------------------------
__global__ __launch_bounds__(64) void viterbi_kernel(
    const float* __restrict__ part,   // [2][T][B][8]
    const float* __restrict__ fc_b,
    const float* __restrict__ start_t,
    const float* __restrict__ end_t,
    const float* __restrict__ trans,  // [8][8]
    int* __restrict__ out)            // [B][T]
{
    int b = blockIdx.x;
    int l = threadIdx.x;
    int j = (l & 3) | ((l >> 1) & 4);
    bool b0c = (l & 1) != 0;
    bool b1c = (l & 2) != 0;
    bool b3c = (l & 8) != 0;
    int sh3 = 3 * j;

    __shared__ unsigned int hist_l[T_];

    float tr[8];
#pragma unroll
    for (int i = 0; i < 8; ++i) tr[i] = trans[i * 8 + j];   // column j
    float endt_r[8];
#pragma unroll
    for (int i = 0; i < 8; ++i) endt_r[i] = end_t[i];
    float fcb = fc_b[j];
    const float* pf = part;
    const float* pb = part + (size_t)T_ * B_ * N_;

    float s[8];

#define SHARE(xx) { \
    float y_ = dppf<QP_XOR1>(xx); \
    float A0 = b0c ? y_ : (xx); float A1 = b0c ? (xx) : y_; \
    float A0x = dppf<QP_XOR2>(A0); float A1x = dppf<QP_XOR2>(A1); \
    float B00 = b1c ? A0x : A0; float B10 = b1c ? A0 : A0x; \
    float B01 = b1c ? A1x : A1; float B11 = b1c ? A1 : A1x; \
    float C00 = dppf<ROW_ROR8>(B00); float C01 = dppf<ROW_ROR8>(B01); \
    float C10 = dppf<ROW_ROR8>(B10); float C11 = dppf<ROW_ROR8>(B11); \
    s[0] = b3c ? C00 : B00;  s[1] = b3c ? C01 : B01; \
    s[2] = b3c ? C10 : B10;  s[3] = b3c ? C11 : B11; \
    s[4] = b3c ? B00 : C00;  s[5] = b3c ? B01 : C01; \
    s[6] = b3c ? B10 : C10;  s[7] = b3c ? B11 : C11; }

#define VSTEP(emv, tcur) { \
    float v0 = (s[0] + tr[0]) + (emv); \
    float v1 = (s[1] + tr[1]) + (emv); \
    float v2 = (s[2] + tr[2]) + (emv); \
    float v3 = (s[3] + tr[3]) + (emv); \
    float v4 = (s[4] + tr[4]) + (emv); \
    float v5 = (s[5] + tr[5]) + (emv); \
    float v6 = (s[6] + tr[6]) + (emv); \
    float v7 = (s[7] + tr[7]) + (emv); \
    float va = (v1 > v0) ? v1 : v0;  int ia = (v1 > v0) ? 1 : 0; \
    float vb = (v3 > v2) ? v3 : v2;  int ib = (v3 > v2) ? 3 : 2; \
    float vc = (v5 > v4) ? v5 : v4;  int ic = (v5 > v4) ? 5 : 4; \
    float vd = (v7 > v6) ? v7 : v6;  int id_ = (v7 > v6) ? 7 : 6; \
    float ve = (vb > va) ? vb : va;  int ie = (vb > va) ? ib : ia; \
    float vf = (vd > vc) ? vd : vc;  int if_ = (vd > vc) ? id_ : ic; \
    float vg = (vf > ve) ? vf : ve;  int ig = (vf > ve) ? if_ : ie; \
    SHARE(vg) \
    unsigned pk = (unsigned)ig << sh3; \
    pk |= (unsigned)dppi<QP_XOR1>((int)pk); \
    pk |= (unsigned)dppi<QP_XOR2>((int)pk); \
    pk |= (unsigned)dppi<ROW_ROR8>((int)pk); \
    if (l == 0) hist_l[tcur] = pk; }

#define LOADSUB(dst, ss) { \
    int t0_ = (ss) * 8; \
    _Pragma("unroll") \
    for (int p = 0; p < 8; ++p) { \
        size_t base = ((size_t)(t0_ + p) * B_ + b) * N_ + j; \
        dst[p] = (pf[base] + pb[base]) + fcb; } }

#define PROC8(arr, t0_) { \
    VSTEP(arr[0], (t0_) + 0) VSTEP(arr[1], (t0_) + 1) \
    VSTEP(arr[2], (t0_) + 2) VSTEP(arr[3], (t0_) + 3) \
    VSTEP(arr[4], (t0_) + 4) VSTEP(arr[5], (t0_) + 5) \
    VSTEP(arr[6], (t0_) + 6) VSTEP(arr[7], (t0_) + 7) }

    float emA[8], emB[8];
    LOADSUB(emA, 0)
    LOADSUB(emB, 1)

    {
        float x0 = start_t[j] + emA[0];
        SHARE(x0)
    }
    VSTEP(emA[1], 1) VSTEP(emA[2], 2) VSTEP(emA[3], 3) VSTEP(emA[4], 4)
    VSTEP(emA[5], 5) VSTEP(emA[6], 6) VSTEP(emA[7], 7)

    for (int ss = 1; ss < 127; ss += 2) {
        LOADSUB(emA, ss + 1)
        PROC8(emB, ss * 8)
        LOADSUB(emB, ss + 2)
        PROC8(emA, (ss + 1) * 8)
    }
    PROC8(emB, 127 * 8)

    int tag;
    {
        float v0 = s[0] + endt_r[0];
        float v1 = s[1] + endt_r[1];
        float v2 = s[2] + endt_r[2];
        float v3 = s[3] + endt_r[3];
        float v4 = s[4] + endt_r[4];
        float v5 = s[5] + endt_r[5];
        float v6 = s[6] + endt_r[6];
        float v7 = s[7] + endt_r[7];
        float va = (v1 > v0) ? v1 : v0;  int ia = (v1 > v0) ? 1 : 0;
        float vb = (v3 > v2) ? v3 : v2;  int ib = (v3 > v2) ? 3 : 2;
        float vc = (v5 > v4) ? v5 : v4;  int ic = (v5 > v4) ? 5 : 4;
        float vd = (v7 > v6) ? v7 : v6;  int id_ = (v7 > v6) ? 7 : 6;
        float ve = (vb > va) ? vb : va;  int ie = (vb > va) ? ib : ia;
        float vf = (vd > vc) ? vd : vc;  int if_ = (vd > vc) ? id_ : ic;
        tag = (vf > ve) ? if_ : ie;
    }
    if (l == 0) out[(size_t)b * T_ + (T_ - 1)] = tag;
    __syncthreads();

    for (int t0b = T_ - 16; t0b >= 0; t0b -= 16) {
        unsigned int pk[16];
#pragma unroll
        for (int qq = 0; qq < 16; ++qq) pk[qq] = hist_l[t0b + qq];
#pragma unroll
        for (int qq = 15; qq >= 0; --qq) {
            int t = t0b + qq;
            if (t >= 1) {
                tag = (pk[qq] >> (3 * tag)) & 7;
                if (l == 0) out[(size_t)b * T_ + t - 1] = tag;
            }
        }
    }
#undef SHARE
#undef VSTEP
#undef LOADSUB
#undef PROC8
}

extern "C" void kernel_launch(void* const* d_in, const int* in_sizes, int n_in,
                              void* d_out, int out_size, void* d_ws, size_t ws_size,
                              hipStream_t stream) {
    (void)in_sizes; (void)n_in; (void)out_size; (void)ws_size;
    const int*   x      = (const int*)  d_in[0];
    const float* emb    = (const float*)d_in[1];
    const float* Wih_f  = (const float*)d_in[2];
    const float* Whh_f  = (const float*)d_in[3];
    const float* b_f    = (const float*)d_in[4];
    const float* Wih_b  = (const float*)d_in[5];
    const float* Whh_b  = (const float*)d_in[6];
    const float* b_b    = (const float*)d_in[7];
    const float* fcW    = (const float*)d_in[8];
    const float* fcb    = (const float*)d_in[9];
    const float* startt = (const float*)d_in[10];
    const float* endt   = (const float*)d_in[11];
    const float* trans  = (const float*)d_in[12];

    float* proj = (float*)d_ws;                    // 2*32*512 floats = 128 KB
    float* part = proj + 2 * V_ * G_;              // 2*1024*64*8 floats = 4 MB
    int*   out  = (int*)d_out;

    proj_kernel<<<64, 512, 0, stream>>>(emb, Wih_f, b_f, Wih_b, b_b, proj);
    lstm_kernel<<<128, 1024, 0, stream>>>(x, Whh_f, Whh_b, proj, fcW, part);
    viterbi_kernel<<<64, 64, 0, stream>>>(part, fcb, startt, endt, trans, out);
}